// Round 8
// baseline (300.832 us; speedup 1.0000x reference)
//
#include <hip/hip_runtime.h>
#include <cstdint>

// B=512, D=256, H=512. out: [512,512] fp32.
// ws: Ai [512*512] f32 (pre-scaled C2) | Aj [512*512] f32 ((..+b1)*C2) | W2q [512*512] i8 swizzled
//     | (optional, if ws_size permits) Xq [8192 tiles x 16 KB] i8 staged layer-1 activations

#define NB 512
#define ND 256
#define NH 512
#define C2 2.885390081777927f  // 2*log2(e): tanh(x) = 1 - 2/(exp2(x*C2)+1)

typedef int i32x4 __attribute__((ext_vector_type(4)));
typedef int i32x16 __attribute__((ext_vector_type(16)));
typedef unsigned int u32;
typedef unsigned char u8;

__device__ __forceinline__ float exp2_fast(float x) {
#if __has_builtin(__builtin_amdgcn_exp2f)
  return __builtin_amdgcn_exp2f(x);
#else
  return exp2f(x);
#endif
}
__device__ __forceinline__ float rcp_fast(float x) {
#if __has_builtin(__builtin_amdgcn_rcpf)
  return __builtin_amdgcn_rcpf(x);
#else
  return 1.0f / x;
#endif
}
__device__ __forceinline__ u32 perm_b32(u32 hi, u32 lo, u32 sel) {
#if __has_builtin(__builtin_amdgcn_perm)
  return __builtin_amdgcn_perm(hi, lo, sel);
#else
  u32 r = 0;
  for (int b = 0; b < 4; ++b) {
    const u32 c = (sel >> (8 * b)) & 255;
    const u32 byte = (c < 4) ? (lo >> (8 * c)) & 255 : (c < 8) ? (hi >> (8 * (c - 4))) & 255 : 0;
    r |= byte << (8 * b);
  }
  return r;
#endif
}
// u pre-scaled by C2: float whose low byte = int8(round(127*tanh(u/C2)))
__device__ __forceinline__ u32 tanh_q127_magic(float u) {
  const float r = rcp_fast(exp2_fast(u) + 1.0f);
  // 12583039 = 1.5*2^23 + 127; result = MAGIC + (127 - 254 r), RNE in the fma; low byte = i8 two's-compl.
  return __builtin_bit_cast(u32, fmaf(-254.0f, r, 12583039.0f));
}

// ---------------- prep v5: blocks 0..511 Ai/Aj GEMM (16i x 32n tiles); 512..575 W2 -> i8 ----------------
__global__ __launch_bounds__(256) void prep_all(const float* __restrict__ h,
                                                const float* __restrict__ W1,
                                                const float* __restrict__ b1,
                                                const float* __restrict__ W2,
                                                float* __restrict__ Ai,
                                                float* __restrict__ Aj,
                                                u8* __restrict__ W2q) {
  const int t = threadIdx.x;
  const int bx = blockIdx.x;
  if (bx < 512) {
    __shared__ float hs[16][68];   // h tile: 16 i x 64 d (padded)
    __shared__ float w1t[64][36];  // W1 rows (d)       x 32 n
    __shared__ float w1b[64][36];  // W1 rows (256 + d) x 32 n
    const int it = bx >> 4, nt = bx & 15;
    const int i0 = it * 16, n0 = nt * 32;
    const int nn = t & 31, ig = t >> 5;  // col nn, rows ig*2..ig*2+1
    float accA[2] = {0.f, 0.f}, accB[2] = {0.f, 0.f};
    for (int c2 = 0; c2 < 4; ++c2) {
      __syncthreads();
      {  // stage h tile 16 x 64
        const int r = t >> 4, c0 = (t & 15) * 4;
        *(float4*)&hs[r][c0] = *(const float4*)(h + (size_t)(i0 + r) * ND + c2 * 64 + c0);
      }
      {  // stage W1 top/bottom tiles 64 x 32
        const int r = t >> 2, c0 = (t & 3) * 8;
        const float* st = W1 + (size_t)(c2 * 64 + r) * NH + n0 + c0;
        const float* sb = W1 + (size_t)(256 + c2 * 64 + r) * NH + n0 + c0;
        const float4 a = *(const float4*)st;
        const float4 b = *(const float4*)(st + 4);
        const float4 c = *(const float4*)sb;
        const float4 d = *(const float4*)(sb + 4);
        *(float4*)&w1t[r][c0] = a;
        *(float4*)&w1t[r][c0 + 4] = b;
        *(float4*)&w1b[r][c0] = c;
        *(float4*)&w1b[r][c0 + 4] = d;
      }
      __syncthreads();
#pragma unroll 4
      for (int k4 = 0; k4 < 16; ++k4) {
        const float4 hv0 = *(const float4*)&hs[ig * 2 + 0][k4 * 4];
        const float4 hv1 = *(const float4*)&hs[ig * 2 + 1][k4 * 4];
        const float* h0 = (const float*)&hv0;
        const float* h1 = (const float*)&hv1;
#pragma unroll
        for (int j = 0; j < 4; ++j) {
          const float wtj = w1t[k4 * 4 + j][nn];
          const float wbj = w1b[k4 * 4 + j][nn];
          accA[0] = fmaf(h0[j], wtj, accA[0]);
          accA[1] = fmaf(h1[j], wtj, accA[1]);
          accB[0] = fmaf(h0[j], wbj, accB[0]);
          accB[1] = fmaf(h1[j], wbj, accB[1]);
        }
      }
    }
    const float b1n = b1[n0 + nn];
#pragma unroll
    for (int r = 0; r < 2; ++r) {
      Ai[(size_t)(i0 + ig * 2 + r) * NH + n0 + nn] = accA[r] * C2;
      Aj[(size_t)(i0 + ig * 2 + r) * NH + n0 + nn] = (accB[r] + b1n) * C2;
    }
  } else {
    // W2 -> i8 (scale 0.25/127), MFMA B-frag order for i8 32x32x32:
    // frag id g = ks*1024 + nt*64 + lane (16 B): byte j = q(W2[ks*32 + (lane>>5)*16 + j][nt*32 + (lane&31)])
    const int g = (bx - 512) * 256 + t;  // 0..16383
    const int lane = g & 63;
    const int nt = (g >> 6) & 15;
    const int ks = g >> 10;
    const int n = nt * 32 + (lane & 31);
    const int kb = ks * 32 + ((lane >> 5) << 4);
    u32 w[4];
#pragma unroll
    for (int q = 0; q < 4; ++q) {
      u32 acc = 0;
#pragma unroll
      for (int j = 0; j < 4; ++j) {
        const float wv = fminf(fmaxf(W2[(kb + q * 4 + j) * NH + n], -0.25f), 0.25f);
        const int qi = (int)rintf(wv * 508.0f);  // 508 = 127/0.25
        acc |= ((u32)(qi & 255)) << (8 * j);
      }
      w[q] = acc;
    }
    ((uint4*)W2q)[g] = make_uint4(w[0], w[1], w[2], w[3]);
  }
}

// ---------------- split path, kernel S: stage all Xq tiles (pure VALU/trans streaming) ----------------
// Tile bx (i = bx>>4, j-tile = bx&15): 16 KB at Xq + bx*16384, slot layout identical to xs.
__global__ __launch_bounds__(512, 8) void stage_xq(const float* __restrict__ Ai,
                                                   const float* __restrict__ Aj,
                                                   u8* __restrict__ Xq) {
  const int t = threadIdx.x;
  const int bx = blockIdx.x;
  const int i = bx >> 4;
  const int j0 = (bx & 15) * 32;
  const int row = t & 31;
  const int s0 = t >> 5;  // 0..15
  const float* ajr = Aj + (size_t)(j0 + row) * NH;
  const float* air = Ai + (size_t)i * NH;
  uint4* xq = (uint4*)(Xq + (size_t)bx * 16384);
#pragma unroll
  for (int uu = 0; uu < 2; ++uu) {
    const int s = s0 + uu * 16;
    const int k0 = s * 16;
    u32 wds[4];
#pragma unroll
    for (int q = 0; q < 4; ++q) {
      const float4 fa = *(const float4*)(ajr + k0 + q * 4);
      const float4 ga = *(const float4*)(air + k0 + q * 4);
      const u32 m0 = tanh_q127_magic(fa.x + ga.x);
      const u32 m1 = tanh_q127_magic(fa.y + ga.y);
      const u32 m2 = tanh_q127_magic(fa.z + ga.z);
      const u32 m3 = tanh_q127_magic(fa.w + ga.w);
      const u32 p01 = perm_b32(m1, m0, 0x0C0C0400u);
      const u32 p23 = perm_b32(m3, m2, 0x0C0C0400u);
      wds[q] = perm_b32(p23, p01, 0x05040100u);
    }
    xq[s * 32 + row] = make_uint4(wds[0], wds[1], wds[2], wds[3]);  // 1 KB contiguous per wave
  }
}

// ---------------- split path, kernel G: i8 GEMM + epilogue, A-frags from global Xq ----------------
// No stage phase, no pre-K barrier, LDS = red only. setprio(1) around the MFMA loop
// (co-resident blocks are at K vs epi phases -> role diversity, the setprio-positive regime).
__global__ __launch_bounds__(512, 8) void gemm_xq(const u8* __restrict__ Xq,
                                                  const u8* __restrict__ W2q,
                                                  const float* __restrict__ b2,
                                                  const float* __restrict__ W3,
                                                  const float* __restrict__ b3,
                                                  float* __restrict__ out) {
  __shared__ float red[8][32];  // 1 KB

  const int t = threadIdx.x;
  const int w = t >> 6;
  const int lane = t & 63;
  const int lhi = lane >> 5;
  const int llo = lane & 31;
  const int bx = blockIdx.x;
  const int i = bx >> 4;
  const int j0 = (bx & 15) * 32;

  i32x16 acc[2];
#pragma unroll
  for (int nt = 0; nt < 2; ++nt)
#pragma unroll
    for (int q = 0; q < 16; ++q) acc[nt][q] = 0;

  const i32x4* xsv = (const i32x4*)(Xq + (size_t)bx * 16384);  // 16 KB tile, L1-resident
  const int abase = lhi * 32 + llo;                            // + ks*64
  const uint4* w2v = (const uint4*)W2q + w * 128 + lane;       // + ks*1024, +64 for ntl=1

  i32x4 aP0 = xsv[abase];
  i32x4 aP1 = xsv[64 + abase];
  uint4 bP00 = w2v[0], bP01 = w2v[64];
  uint4 bP10 = w2v[1024], bP11 = w2v[1024 + 64];

  __builtin_amdgcn_s_setprio(1);
#pragma unroll
  for (int kk = 0; kk < 8; ++kk) {
    const int ks0 = 2 * kk;
    {
      const i32x4 a = aP0;
      const i32x4 c0 = __builtin_bit_cast(i32x4, bP00);
      const i32x4 c1 = __builtin_bit_cast(i32x4, bP01);
      if (kk < 7) {
        aP0 = xsv[(ks0 + 2) * 64 + abase];
        const uint4* wp = w2v + (ks0 + 2) * 1024;
        bP00 = wp[0];
        bP01 = wp[64];
      }
      acc[0] = __builtin_amdgcn_mfma_i32_32x32x32_i8(a, c0, acc[0], 0, 0, 0);
      acc[1] = __builtin_amdgcn_mfma_i32_32x32x32_i8(a, c1, acc[1], 0, 0, 0);
    }
    {
      const i32x4 a = aP1;
      const i32x4 c0 = __builtin_bit_cast(i32x4, bP10);
      const i32x4 c1 = __builtin_bit_cast(i32x4, bP11);
      if (kk < 7) {
        aP1 = xsv[(ks0 + 3) * 64 + abase];
        const uint4* wp = w2v + (ks0 + 3) * 1024;
        bP10 = wp[0];
        bP11 = wp[64];
      }
      acc[0] = __builtin_amdgcn_mfma_i32_32x32x32_i8(a, c0, acc[0], 0, 0, 0);
      acc[1] = __builtin_amdgcn_mfma_i32_32x32x32_i8(a, c1, acc[1], 0, 0, 0);
    }
  }
  __builtin_amdgcn_s_setprio(0);

  // ---- epilogue: y = acc*SCALE + b2*C2; r = 1/(exp2(y)+1); partial = Σw3 - 2 Σ w3·r ----
  const float SCALE = (0.25f / (127.0f * 127.0f)) * C2;
  float b2c[2], w3v[2];
#pragma unroll
  for (int ntl = 0; ntl < 2; ++ntl) {
    const int n = w * 64 + ntl * 32 + llo;
    b2c[ntl] = b2[n] * C2;
    w3v[ntl] = W3[n];
  }
  float w3s = w3v[0] + w3v[1];
#pragma unroll
  for (int off = 1; off < 32; off <<= 1) w3s += __shfl_xor(w3s, off, 64);  // Σ w3 over wave's 64 n

#pragma unroll
  for (int reg = 0; reg < 16; ++reg) {
    float sr = 0.0f;
#pragma unroll
    for (int ntl = 0; ntl < 2; ++ntl) {
      const float y = fmaf((float)acc[ntl][reg], SCALE, b2c[ntl]);
      const float r = rcp_fast(exp2_fast(y) + 1.0f);
      sr = fmaf(w3v[ntl], r, sr);
    }
#pragma unroll
    for (int off = 1; off < 32; off <<= 1) sr += __shfl_xor(sr, off, 64);
    const int row = (reg & 3) + 8 * (reg >> 2) + 4 * lhi;  // 0..31
    if (llo == reg) red[w][row] = fmaf(-2.0f, sr, w3s);
  }
  __syncthreads();
  if (t < 32) {
    float v = b3[0];
#pragma unroll
    for (int ww = 0; ww < 8; ++ww) v += red[ww][t];
    const int j = j0 + t;
    out[i * NB + j] = (j == i) ? -20.0f : v;
  }
}

// ---------------- fallback (ws too small): R7 fused pair_main, verbatim (proven 167.5 us) ----------------
__global__ __launch_bounds__(512, 6) void pair_main(const float* __restrict__ Ai,
                                                    const float* __restrict__ Aj,
                                                    const u8* __restrict__ W2q,
                                                    const float* __restrict__ b2,
                                                    const float* __restrict__ W3,
                                                    const float* __restrict__ b3,
                                                    float* __restrict__ out) {
  __shared__ __align__(16) u8 xs[32 * 512];  // 16 KB
  __shared__ float red[8][32];               // 1 KB

  const int t = threadIdx.x;
  const int w = t >> 6;
  const int lane = t & 63;
  const int lhi = lane >> 5;
  const int llo = lane & 31;
  const int bx = blockIdx.x;
  const int i = bx >> 4;
  const int j0 = (bx & 15) * 32;

  i32x16 acc[2];
#pragma unroll
  for (int nt = 0; nt < 2; ++nt)
#pragma unroll
    for (int q = 0; q < 16; ++q) acc[nt][q] = 0;

  {
    const int row = t & 31;
    const int s0 = t >> 5;  // 0..15
    const float* ajr = Aj + (size_t)(j0 + row) * NH;
    const float* air = Ai + (size_t)i * NH;
#pragma unroll
    for (int uu = 0; uu < 2; ++uu) {
      const int s = s0 + uu * 16;
      const int k0 = s * 16;
      u32 wds[4];
#pragma unroll
      for (int q = 0; q < 4; ++q) {
        const float4 fa = *(const float4*)(ajr + k0 + q * 4);
        const float4 ga = *(const float4*)(air + k0 + q * 4);
        const u32 m0 = tanh_q127_magic(fa.x + ga.x);
        const u32 m1 = tanh_q127_magic(fa.y + ga.y);
        const u32 m2 = tanh_q127_magic(fa.z + ga.z);
        const u32 m3 = tanh_q127_magic(fa.w + ga.w);
        const u32 p01 = perm_b32(m1, m0, 0x0C0C0400u);
        const u32 p23 = perm_b32(m3, m2, 0x0C0C0400u);
        wds[q] = perm_b32(p23, p01, 0x05040100u);
      }
      ((uint4*)xs)[s * 32 + row] = make_uint4(wds[0], wds[1], wds[2], wds[3]);
    }
  }
  __syncthreads();

  const i32x4* xsv = (const i32x4*)xs;
  const int abase = lhi * 32 + llo;                       // + ks*64
  const uint4* w2v = (const uint4*)W2q + w * 128 + lane;  // + ks*1024, +64 for ntl=1

  i32x4 aP0 = xsv[abase];
  i32x4 aP1 = xsv[64 + abase];
  uint4 bP00 = w2v[0], bP01 = w2v[64];
  uint4 bP10 = w2v[1024], bP11 = w2v[1024 + 64];

#pragma unroll
  for (int kk = 0; kk < 8; ++kk) {
    const int ks0 = 2 * kk;
    {
      const i32x4 a = aP0;
      const i32x4 c0 = __builtin_bit_cast(i32x4, bP00);
      const i32x4 c1 = __builtin_bit_cast(i32x4, bP01);
      if (kk < 7) {
        aP0 = xsv[(ks0 + 2) * 64 + abase];
        const uint4* wp = w2v + (ks0 + 2) * 1024;
        bP00 = wp[0];
        bP01 = wp[64];
      }
      acc[0] = __builtin_amdgcn_mfma_i32_32x32x32_i8(a, c0, acc[0], 0, 0, 0);
      acc[1] = __builtin_amdgcn_mfma_i32_32x32x32_i8(a, c1, acc[1], 0, 0, 0);
    }
    {
      const i32x4 a = aP1;
      const i32x4 c0 = __builtin_bit_cast(i32x4, bP10);
      const i32x4 c1 = __builtin_bit_cast(i32x4, bP11);
      if (kk < 7) {
        aP1 = xsv[(ks0 + 3) * 64 + abase];
        const uint4* wp = w2v + (ks0 + 3) * 1024;
        bP10 = wp[0];
        bP11 = wp[64];
      }
      acc[0] = __builtin_amdgcn_mfma_i32_32x32x32_i8(a, c0, acc[0], 0, 0, 0);
      acc[1] = __builtin_amdgcn_mfma_i32_32x32x32_i8(a, c1, acc[1], 0, 0, 0);
    }
  }

  const float SCALE = (0.25f / (127.0f * 127.0f)) * C2;
  float b2c[2], w3v[2];
#pragma unroll
  for (int ntl = 0; ntl < 2; ++ntl) {
    const int n = w * 64 + ntl * 32 + llo;
    b2c[ntl] = b2[n] * C2;
    w3v[ntl] = W3[n];
  }
  float w3s = w3v[0] + w3v[1];
#pragma unroll
  for (int off = 1; off < 32; off <<= 1) w3s += __shfl_xor(w3s, off, 64);

#pragma unroll
  for (int reg = 0; reg < 16; ++reg) {
    float sr = 0.0f;
#pragma unroll
    for (int ntl = 0; ntl < 2; ++ntl) {
      const float y = fmaf((float)acc[ntl][reg], SCALE, b2c[ntl]);
      const float r = rcp_fast(exp2_fast(y) + 1.0f);
      sr = fmaf(w3v[ntl], r, sr);
    }
#pragma unroll
    for (int off = 1; off < 32; off <<= 1) sr += __shfl_xor(sr, off, 64);
    const int row = (reg & 3) + 8 * (reg >> 2) + 4 * lhi;  // 0..31
    if (llo == reg) red[w][row] = fmaf(-2.0f, sr, w3s);
  }
  __syncthreads();
  if (t < 32) {
    float v = b3[0];
#pragma unroll
    for (int ww = 0; ww < 8; ++ww) v += red[ww][t];
    const int j = j0 + t;
    out[i * NB + j] = (j == i) ? -20.0f : v;
  }
}

extern "C" void kernel_launch(void* const* d_in, const int* in_sizes, int n_in,
                              void* d_out, int out_size, void* d_ws, size_t ws_size,
                              hipStream_t stream) {
  const float* h = (const float*)d_in[0];
  const float* W1 = (const float*)d_in[1];
  const float* b1 = (const float*)d_in[2];
  const float* W2 = (const float*)d_in[3];
  const float* b2 = (const float*)d_in[4];
  const float* W3 = (const float*)d_in[5];
  const float* b3 = (const float*)d_in[6];
  float* out = (float*)d_out;

  float* Ai = (float*)d_ws;
  float* Aj = Ai + NB * NH;
  u8* W2q = (u8*)(Aj + NB * NH);
  u8* Xq = W2q + NB * NH;

  const size_t XQ_OFF = (size_t)NB * NH * 4 * 2 + (size_t)NB * NH;  // 2.25 MB
  const size_t XQ_BYTES = (size_t)8192 * 16384;                     // 134.2 MB

  prep_all<<<576, 256, 0, stream>>>(h, W1, b1, W2, Ai, Aj, W2q);

  if (ws_size >= XQ_OFF + XQ_BYTES) {
    stage_xq<<<8192, 512, 0, stream>>>(Ai, Aj, Xq);
    gemm_xq<<<8192, 512, 0, stream>>>(Xq, W2q, b2, W3, b3, out);
  } else {
    pair_main<<<8192, 512, 0, stream>>>(Ai, Aj, W2q, b2, W3, b3, out);
  }
}

// Round 9
// 216.535 us; speedup vs baseline: 1.3893x; 1.3893x over previous
//
#include <hip/hip_runtime.h>
#include <cstdint>

// B=512, D=256, H=512. out: [512,512] fp32.
// ws: Ai [512*512] f32 (pre-scaled C2) | Aj [512*512] f32 ((..+b1)*C2) | W2q [512*512] i8 swizzled

#define NB 512
#define ND 256
#define NH 512
#define C2 2.885390081777927f  // 2*log2(e): tanh(x) = 1 - 2/(exp2(x*C2)+1)

typedef int i32x4 __attribute__((ext_vector_type(4)));
typedef int i32x16 __attribute__((ext_vector_type(16)));
typedef unsigned int u32;
typedef unsigned char u8;

__device__ __forceinline__ float exp2_fast(float x) {
#if __has_builtin(__builtin_amdgcn_exp2f)
  return __builtin_amdgcn_exp2f(x);
#else
  return exp2f(x);
#endif
}
__device__ __forceinline__ float rcp_fast(float x) {
#if __has_builtin(__builtin_amdgcn_rcpf)
  return __builtin_amdgcn_rcpf(x);
#else
  return 1.0f / x;
#endif
}
__device__ __forceinline__ u32 perm_b32(u32 hi, u32 lo, u32 sel) {
#if __has_builtin(__builtin_amdgcn_perm)
  return __builtin_amdgcn_perm(hi, lo, sel);
#else
  u32 r = 0;
  for (int b = 0; b < 4; ++b) {
    const u32 c = (sel >> (8 * b)) & 255;
    const u32 byte = (c < 4) ? (lo >> (8 * c)) & 255 : (c < 8) ? (hi >> (8 * (c - 4))) & 255 : 0;
    r |= byte << (8 * b);
  }
  return r;
#endif
}
// u pre-scaled by C2: float whose low byte = int8(round(127*tanh(u/C2)))
__device__ __forceinline__ u32 tanh_q127_magic(float u) {
  const float r = rcp_fast(exp2_fast(u) + 1.0f);
  // 12583039 = 1.5*2^23 + 127; result = MAGIC + (127 - 254 r), RNE in the fma; low byte = i8 two's-compl.
  return __builtin_bit_cast(u32, fmaf(-254.0f, r, 12583039.0f));
}

// Sum over each 32-lane half of the wave via DPP row-shifts (pure VALU pipe, no DS).
// Result valid in lane 31 (lanes 0-31 sum) and lane 63 (lanes 32-63 sum).
__device__ __forceinline__ float half32_sum(float s) {
#if __has_builtin(__builtin_amdgcn_update_dpp)
#define DPP_ADD(ctrl) \
  s += __builtin_bit_cast(float, __builtin_amdgcn_update_dpp(0, __builtin_bit_cast(int, s), ctrl, 0xF, 0xF, true))
  DPP_ADD(0x111);  // row_shr:1
  DPP_ADD(0x112);  // row_shr:2
  DPP_ADD(0x114);  // row_shr:4
  DPP_ADD(0x118);  // row_shr:8  -> lane15/31/47/63 hold their row-16 sums
  DPP_ADD(0x142);  // row_bcast:15 -> lane31 += lane15, lane63 += lane47
#undef DPP_ADD
  return s;
#else
  for (int off = 1; off < 32; off <<= 1) s += __shfl_xor(s, off, 64);
  return s;  // valid in all lanes (superset)
#endif
}

// ---------------- prep v5: blocks 0..511 Ai/Aj GEMM (16i x 32n tiles); 512..575 W2 -> i8 ----------------
__global__ __launch_bounds__(256) void prep_all(const float* __restrict__ h,
                                                const float* __restrict__ W1,
                                                const float* __restrict__ b1,
                                                const float* __restrict__ W2,
                                                float* __restrict__ Ai,
                                                float* __restrict__ Aj,
                                                u8* __restrict__ W2q) {
  const int t = threadIdx.x;
  const int bx = blockIdx.x;
  if (bx < 512) {
    __shared__ float hs[16][68];   // h tile: 16 i x 64 d (padded)
    __shared__ float w1t[64][36];  // W1 rows (d)       x 32 n
    __shared__ float w1b[64][36];  // W1 rows (256 + d) x 32 n
    const int it = bx >> 4, nt = bx & 15;
    const int i0 = it * 16, n0 = nt * 32;
    const int nn = t & 31, ig = t >> 5;  // col nn, rows ig*2..ig*2+1
    float accA[2] = {0.f, 0.f}, accB[2] = {0.f, 0.f};
    for (int c2 = 0; c2 < 4; ++c2) {
      __syncthreads();
      {  // stage h tile 16 x 64
        const int r = t >> 4, c0 = (t & 15) * 4;
        *(float4*)&hs[r][c0] = *(const float4*)(h + (size_t)(i0 + r) * ND + c2 * 64 + c0);
      }
      {  // stage W1 top/bottom tiles 64 x 32
        const int r = t >> 2, c0 = (t & 3) * 8;
        const float* st = W1 + (size_t)(c2 * 64 + r) * NH + n0 + c0;
        const float* sb = W1 + (size_t)(256 + c2 * 64 + r) * NH + n0 + c0;
        const float4 a = *(const float4*)st;
        const float4 b = *(const float4*)(st + 4);
        const float4 c = *(const float4*)sb;
        const float4 d = *(const float4*)(sb + 4);
        *(float4*)&w1t[r][c0] = a;
        *(float4*)&w1t[r][c0 + 4] = b;
        *(float4*)&w1b[r][c0] = c;
        *(float4*)&w1b[r][c0 + 4] = d;
      }
      __syncthreads();
#pragma unroll 4
      for (int k4 = 0; k4 < 16; ++k4) {
        const float4 hv0 = *(const float4*)&hs[ig * 2 + 0][k4 * 4];
        const float4 hv1 = *(const float4*)&hs[ig * 2 + 1][k4 * 4];
        const float* h0 = (const float*)&hv0;
        const float* h1 = (const float*)&hv1;
#pragma unroll
        for (int j = 0; j < 4; ++j) {
          const float wtj = w1t[k4 * 4 + j][nn];
          const float wbj = w1b[k4 * 4 + j][nn];
          accA[0] = fmaf(h0[j], wtj, accA[0]);
          accA[1] = fmaf(h1[j], wtj, accA[1]);
          accB[0] = fmaf(h0[j], wbj, accB[0]);
          accB[1] = fmaf(h1[j], wbj, accB[1]);
        }
      }
    }
    const float b1n = b1[n0 + nn];
#pragma unroll
    for (int r = 0; r < 2; ++r) {
      Ai[(size_t)(i0 + ig * 2 + r) * NH + n0 + nn] = accA[r] * C2;
      Aj[(size_t)(i0 + ig * 2 + r) * NH + n0 + nn] = (accB[r] + b1n) * C2;
    }
  } else {
    // W2 -> i8 (scale 0.25/127), MFMA B-frag order for i8 32x32x32:
    // frag id g = ks*1024 + nt*64 + lane (16 B): byte j = q(W2[ks*32 + (lane>>5)*16 + j][nt*32 + (lane&31)])
    const int g = (bx - 512) * 256 + t;  // 0..16383
    const int lane = g & 63;
    const int nt = (g >> 6) & 15;
    const int ks = g >> 10;
    const int n = nt * 32 + (lane & 31);
    const int kb = ks * 32 + ((lane >> 5) << 4);
    u32 w[4];
#pragma unroll
    for (int q = 0; q < 4; ++q) {
      u32 acc = 0;
#pragma unroll
      for (int j = 0; j < 4; ++j) {
        const float wv = fminf(fmaxf(W2[(kb + q * 4 + j) * NH + n], -0.25f), 0.25f);
        const int qi = (int)rintf(wv * 508.0f);  // 508 = 127/0.25
        acc |= ((u32)(qi & 255)) << (8 * j);
      }
      w[q] = acc;
    }
    ((uint4*)W2q)[g] = make_uint4(w[0], w[1], w[2], w[3]);
  }
}

// ---------------- main: R7 fused kernel + DPP epilogue reduce (no DS swizzles in epilogue) ----------------
// Block: one i, 32 j's (M=32), N=512, K=512 (16 ks-steps of 32). Wave w: 2 n-tiles nt = w*2+{0,1}.
// X LDS: 16-B slot idx = s*32 + row, s = k>>4; byte j of slot = i8(127*tanh(X[row][s*16+j])).
// A frag (ks): i32x4 at idx ks*64 + (lane>>5)*32 + (lane&31).
// B frag (ks,ntl): uint4 at W2q frag id ks*1024 + (w*2+ntl)*64 + lane.
// K-loop: ping-pong x2 unroll, SSA register sets, prefetch distance 2, no barriers.
// Epilogue: per-reg 32-lane sums via DPP row-shr chain (VALU, ~20 cy dep chain) instead of
// 5-level ds_swizzle (~150+ cy, DS pipe); result lanes 31/63 write red[][] directly.
__global__ __launch_bounds__(512, 6) void pair_main(const float* __restrict__ Ai,
                                                    const float* __restrict__ Aj,
                                                    const u8* __restrict__ W2q,
                                                    const float* __restrict__ b2,
                                                    const float* __restrict__ W3,
                                                    const float* __restrict__ b3,
                                                    float* __restrict__ out) {
  __shared__ __align__(16) u8 xs[32 * 512];  // 16 KB
  __shared__ float red[8][32];               // 1 KB

  const int t = threadIdx.x;
  const int w = t >> 6;
  const int lane = t & 63;
  const int lhi = lane >> 5;
  const int llo = lane & 31;
  const int bx = blockIdx.x;
  const int i = bx >> 4;
  const int j0 = (bx & 15) * 32;

  i32x16 acc[2];
#pragma unroll
  for (int nt = 0; nt < 2; ++nt)
#pragma unroll
    for (int q = 0; q < 16; ++q) acc[nt][q] = 0;

  // ---- stage X: thread t -> row = t&31, slots s in {t>>5, (t>>5)+16} (16 k's each) ----
  {
    const int row = t & 31;
    const int s0 = t >> 5;  // 0..15
    const float* ajr = Aj + (size_t)(j0 + row) * NH;
    const float* air = Ai + (size_t)i * NH;
#pragma unroll
    for (int uu = 0; uu < 2; ++uu) {
      const int s = s0 + uu * 16;
      const int k0 = s * 16;
      u32 wds[4];
#pragma unroll
      for (int q = 0; q < 4; ++q) {
        const float4 fa = *(const float4*)(ajr + k0 + q * 4);
        const float4 ga = *(const float4*)(air + k0 + q * 4);
        const u32 m0 = tanh_q127_magic(fa.x + ga.x);
        const u32 m1 = tanh_q127_magic(fa.y + ga.y);
        const u32 m2 = tanh_q127_magic(fa.z + ga.z);
        const u32 m3 = tanh_q127_magic(fa.w + ga.w);
        const u32 p01 = perm_b32(m1, m0, 0x0C0C0400u);
        const u32 p23 = perm_b32(m3, m2, 0x0C0C0400u);
        wds[q] = perm_b32(p23, p01, 0x05040100u);
      }
      ((uint4*)xs)[s * 32 + row] = make_uint4(wds[0], wds[1], wds[2], wds[3]);
    }
  }
  __syncthreads();  // only block-wide barrier before epilogue

  // ---- K-loop ----
  const i32x4* xsv = (const i32x4*)xs;
  const int abase = lhi * 32 + llo;                       // + ks*64
  const uint4* w2v = (const uint4*)W2q + w * 128 + lane;  // + ks*1024, +64 for ntl=1

  i32x4 aP0 = xsv[abase];
  i32x4 aP1 = xsv[64 + abase];
  uint4 bP00 = w2v[0], bP01 = w2v[64];
  uint4 bP10 = w2v[1024], bP11 = w2v[1024 + 64];

#pragma unroll
  for (int kk = 0; kk < 8; ++kk) {
    const int ks0 = 2 * kk;
    {
      const i32x4 a = aP0;
      const i32x4 c0 = __builtin_bit_cast(i32x4, bP00);
      const i32x4 c1 = __builtin_bit_cast(i32x4, bP01);
      if (kk < 7) {
        aP0 = xsv[(ks0 + 2) * 64 + abase];
        const uint4* wp = w2v + (ks0 + 2) * 1024;
        bP00 = wp[0];
        bP01 = wp[64];
      }
      acc[0] = __builtin_amdgcn_mfma_i32_32x32x32_i8(a, c0, acc[0], 0, 0, 0);
      acc[1] = __builtin_amdgcn_mfma_i32_32x32x32_i8(a, c1, acc[1], 0, 0, 0);
    }
    {
      const i32x4 a = aP1;
      const i32x4 c0 = __builtin_bit_cast(i32x4, bP10);
      const i32x4 c1 = __builtin_bit_cast(i32x4, bP11);
      if (kk < 7) {
        aP1 = xsv[(ks0 + 3) * 64 + abase];
        const uint4* wp = w2v + (ks0 + 3) * 1024;
        bP10 = wp[0];
        bP11 = wp[64];
      }
      acc[0] = __builtin_amdgcn_mfma_i32_32x32x32_i8(a, c0, acc[0], 0, 0, 0);
      acc[1] = __builtin_amdgcn_mfma_i32_32x32x32_i8(a, c1, acc[1], 0, 0, 0);
    }
  }

  // ---- epilogue: y = acc*SCALE + b2*C2; r = 1/(exp2(y)+1); partial = Σw3 - 2 Σ w3·r ----
  const float SCALE = (0.25f / (127.0f * 127.0f)) * C2;
  float b2c[2], w3v[2];
#pragma unroll
  for (int ntl = 0; ntl < 2; ++ntl) {
    const int n = w * 64 + ntl * 32 + llo;
    b2c[ntl] = b2[n] * C2;
    w3v[ntl] = W3[n];
  }
  const float w3s = half32_sum(w3v[0] + w3v[1]);  // valid in lanes 31/63 (each = Σ over wave's 64 n)

#pragma unroll
  for (int reg = 0; reg < 16; ++reg) {
    float sr = 0.0f;
#pragma unroll
    for (int ntl = 0; ntl < 2; ++ntl) {
      const float y = fmaf((float)acc[ntl][reg], SCALE, b2c[ntl]);
      const float r = rcp_fast(exp2_fast(y) + 1.0f);
      sr = fmaf(w3v[ntl], r, sr);
    }
    sr = half32_sum(sr);  // lanes 31/63 hold the 32-lane sums for lhi = 0/1
    const int row = (reg & 3) + 8 * (reg >> 2) + 4 * lhi;  // 0..31
    if (llo == 31) red[w][row] = fmaf(-2.0f, sr, w3s);
  }
  __syncthreads();
  if (t < 32) {
    float v = b3[0];
#pragma unroll
    for (int ww = 0; ww < 8; ++ww) v += red[ww][t];
    const int j = j0 + t;
    out[i * NB + j] = (j == i) ? -20.0f : v;
  }
}

extern "C" void kernel_launch(void* const* d_in, const int* in_sizes, int n_in,
                              void* d_out, int out_size, void* d_ws, size_t ws_size,
                              hipStream_t stream) {
  const float* h = (const float*)d_in[0];
  const float* W1 = (const float*)d_in[1];
  const float* b1 = (const float*)d_in[2];
  const float* W2 = (const float*)d_in[3];
  const float* b2 = (const float*)d_in[4];
  const float* W3 = (const float*)d_in[5];
  const float* b3 = (const float*)d_in[6];
  float* out = (float*)d_out;

  float* Ai = (float*)d_ws;
  float* Aj = Ai + NB * NH;
  u8* W2q = (u8*)(Aj + NB * NH);

  prep_all<<<576, 256, 0, stream>>>(h, W1, b1, W2, Ai, Aj, W2q);
  pair_main<<<8192, 512, 0, stream>>>(Ai, Aj, W2q, b2, W3, b3, out);
}

// Round 10
// 215.643 us; speedup vs baseline: 1.3950x; 1.0041x over previous
//
#include <hip/hip_runtime.h>
#include <cstdint>

// B=512, D=256, H=512. out: [512,512] fp32.
// ws: Ei [512*512] f32 = exp2(C2*ai) | Ej [512*512] f32 = exp2(C2*(aj+b1)) | W2q [512*512] i8 swizzled

#define NB 512
#define ND 256
#define NH 512
#define C2 2.885390081777927f  // 2*log2(e): tanh(x) = 1 - 2/(exp2(x*C2)+1)

typedef int i32x4 __attribute__((ext_vector_type(4)));
typedef int i32x16 __attribute__((ext_vector_type(16)));
typedef unsigned int u32;
typedef unsigned char u8;

__device__ __forceinline__ float exp2_fast(float x) {
#if __has_builtin(__builtin_amdgcn_exp2f)
  return __builtin_amdgcn_exp2f(x);
#else
  return exp2f(x);
#endif
}
__device__ __forceinline__ float rcp_fast(float x) {
#if __has_builtin(__builtin_amdgcn_rcpf)
  return __builtin_amdgcn_rcpf(x);
#else
  return 1.0f / x;
#endif
}
__device__ __forceinline__ u32 perm_b32(u32 hi, u32 lo, u32 sel) {
#if __has_builtin(__builtin_amdgcn_perm)
  return __builtin_amdgcn_perm(hi, lo, sel);
#else
  u32 r = 0;
  for (int b = 0; b < 4; ++b) {
    const u32 c = (sel >> (8 * b)) & 255;
    const u32 byte = (c < 4) ? (lo >> (8 * c)) & 255 : (c < 8) ? (hi >> (8 * (c - 4))) & 255 : 0;
    r |= byte << (8 * b);
  }
  return r;
#endif
}
// r = 1/(e+1) precomputed; float whose low byte = int8(round(127*tanh)) via RNE in the fma
__device__ __forceinline__ u32 tanh_magic_from_r(float r) {
  // 12583039 = 1.5*2^23 + 127; result = MAGIC + (127 - 254 r); low byte = i8 two's-compl.
  return __builtin_bit_cast(u32, fmaf(-254.0f, r, 12583039.0f));
}

// Sum over each 32-lane half of the wave via DPP row-shifts (pure VALU pipe, no DS).
// Result valid in lane 31 (lanes 0-31 sum) and lane 63 (lanes 32-63 sum).
__device__ __forceinline__ float half32_sum(float s) {
#if __has_builtin(__builtin_amdgcn_update_dpp)
#define DPP_ADD(ctrl) \
  s += __builtin_bit_cast(float, __builtin_amdgcn_update_dpp(0, __builtin_bit_cast(int, s), ctrl, 0xF, 0xF, true))
  DPP_ADD(0x111);  // row_shr:1
  DPP_ADD(0x112);  // row_shr:2
  DPP_ADD(0x114);  // row_shr:4
  DPP_ADD(0x118);  // row_shr:8  -> lane15/31/47/63 hold their row-16 sums
  DPP_ADD(0x142);  // row_bcast:15 -> lane31 += lane15, lane63 += lane47
#undef DPP_ADD
  return s;
#else
  for (int off = 1; off < 32; off <<= 1) s += __shfl_xor(s, off, 64);
  return s;  // valid in all lanes (superset)
#endif
}

// ---------------- prep v6: blocks 0..511 Ei/Ej GEMM (16i x 32n tiles); 512..575 W2 -> i8 ----------------
// Ei = exp2(C2*ai), Ej = exp2(C2*(aj+b1)): staging exp2 hoisted here (exp2(a+b) = exp2(a)*exp2(b)).
__global__ __launch_bounds__(256) void prep_all(const float* __restrict__ h,
                                                const float* __restrict__ W1,
                                                const float* __restrict__ b1,
                                                const float* __restrict__ W2,
                                                float* __restrict__ Ei,
                                                float* __restrict__ Ej,
                                                u8* __restrict__ W2q) {
  const int t = threadIdx.x;
  const int bx = blockIdx.x;
  if (bx < 512) {
    __shared__ float hs[16][68];   // h tile: 16 i x 64 d (padded)
    __shared__ float w1t[64][36];  // W1 rows (d)       x 32 n
    __shared__ float w1b[64][36];  // W1 rows (256 + d) x 32 n
    const int it = bx >> 4, nt = bx & 15;
    const int i0 = it * 16, n0 = nt * 32;
    const int nn = t & 31, ig = t >> 5;  // col nn, rows ig*2..ig*2+1
    float accA[2] = {0.f, 0.f}, accB[2] = {0.f, 0.f};
    for (int c2 = 0; c2 < 4; ++c2) {
      __syncthreads();
      {  // stage h tile 16 x 64
        const int r = t >> 4, c0 = (t & 15) * 4;
        *(float4*)&hs[r][c0] = *(const float4*)(h + (size_t)(i0 + r) * ND + c2 * 64 + c0);
      }
      {  // stage W1 top/bottom tiles 64 x 32
        const int r = t >> 2, c0 = (t & 3) * 8;
        const float* st = W1 + (size_t)(c2 * 64 + r) * NH + n0 + c0;
        const float* sb = W1 + (size_t)(256 + c2 * 64 + r) * NH + n0 + c0;
        const float4 a = *(const float4*)st;
        const float4 b = *(const float4*)(st + 4);
        const float4 c = *(const float4*)sb;
        const float4 d = *(const float4*)(sb + 4);
        *(float4*)&w1t[r][c0] = a;
        *(float4*)&w1t[r][c0 + 4] = b;
        *(float4*)&w1b[r][c0] = c;
        *(float4*)&w1b[r][c0 + 4] = d;
      }
      __syncthreads();
#pragma unroll 4
      for (int k4 = 0; k4 < 16; ++k4) {
        const float4 hv0 = *(const float4*)&hs[ig * 2 + 0][k4 * 4];
        const float4 hv1 = *(const float4*)&hs[ig * 2 + 1][k4 * 4];
        const float* h0 = (const float*)&hv0;
        const float* h1 = (const float*)&hv1;
#pragma unroll
        for (int j = 0; j < 4; ++j) {
          const float wtj = w1t[k4 * 4 + j][nn];
          const float wbj = w1b[k4 * 4 + j][nn];
          accA[0] = fmaf(h0[j], wtj, accA[0]);
          accA[1] = fmaf(h1[j], wtj, accA[1]);
          accB[0] = fmaf(h0[j], wbj, accB[0]);
          accB[1] = fmaf(h1[j], wbj, accB[1]);
        }
      }
    }
    const float b1n = b1[n0 + nn];
#pragma unroll
    for (int r = 0; r < 2; ++r) {
      Ei[(size_t)(i0 + ig * 2 + r) * NH + n0 + nn] = exp2_fast(accA[r] * C2);
      Ej[(size_t)(i0 + ig * 2 + r) * NH + n0 + nn] = exp2_fast((accB[r] + b1n) * C2);
    }
  } else {
    // W2 -> i8 (scale 0.25/127), MFMA B-frag order for i8 32x32x32:
    // frag id g = ks*1024 + nt*64 + lane (16 B): byte j = q(W2[ks*32 + (lane>>5)*16 + j][nt*32 + (lane&31)])
    const int g = (bx - 512) * 256 + t;  // 0..16383
    const int lane = g & 63;
    const int nt = (g >> 6) & 15;
    const int ks = g >> 10;
    const int n = nt * 32 + (lane & 31);
    const int kb = ks * 32 + ((lane >> 5) << 4);
    u32 w[4];
#pragma unroll
    for (int q = 0; q < 4; ++q) {
      u32 acc = 0;
#pragma unroll
      for (int j = 0; j < 4; ++j) {
        const float wv = fminf(fmaxf(W2[(kb + q * 4 + j) * NH + n], -0.25f), 0.25f);
        const int qi = (int)rintf(wv * 508.0f);  // 508 = 127/0.25
        acc |= ((u32)(qi & 255)) << (8 * j);
      }
      w[q] = acc;
    }
    ((uint4*)W2q)[g] = make_uint4(w[0], w[1], w[2], w[3]);
  }
}

// ---------------- main: R7 structure + DPP reduce + trans-diet ----------------
// Staging: e+1 = fmaf(Ej,Ei,1) (no exp2); reciprocals paired (1 rcp + 3 mul per 2 evals).
// Epilogue: exp2 unavoidable; rcp paired across ntl. Everything else identical to R9.
__global__ __launch_bounds__(512, 6) void pair_main(const float* __restrict__ Ei,
                                                    const float* __restrict__ Ej,
                                                    const u8* __restrict__ W2q,
                                                    const float* __restrict__ b2,
                                                    const float* __restrict__ W3,
                                                    const float* __restrict__ b3,
                                                    float* __restrict__ out) {
  __shared__ __align__(16) u8 xs[32 * 512];  // 16 KB
  __shared__ float red[8][32];               // 1 KB

  const int t = threadIdx.x;
  const int w = t >> 6;
  const int lane = t & 63;
  const int lhi = lane >> 5;
  const int llo = lane & 31;
  const int bx = blockIdx.x;
  const int i = bx >> 4;
  const int j0 = (bx & 15) * 32;

  i32x16 acc[2];
#pragma unroll
  for (int nt = 0; nt < 2; ++nt)
#pragma unroll
    for (int q = 0; q < 16; ++q) acc[nt][q] = 0;

  // ---- stage X: thread t -> row = t&31, slots s in {t>>5, (t>>5)+16} (16 k's each) ----
  {
    const int row = t & 31;
    const int s0 = t >> 5;  // 0..15
    const float* ajr = Ej + (size_t)(j0 + row) * NH;
    const float* air = Ei + (size_t)i * NH;
#pragma unroll
    for (int uu = 0; uu < 2; ++uu) {
      const int s = s0 + uu * 16;
      const int k0 = s * 16;
      u32 wds[4];
#pragma unroll
      for (int q = 0; q < 4; ++q) {
        const float4 fa = *(const float4*)(ajr + k0 + q * 4);
        const float4 ga = *(const float4*)(air + k0 + q * 4);
        // e+1 in one fma each (exp2 hoisted to prep: e = Ej*Ei)
        const float e0 = fmaf(fa.x, ga.x, 1.0f);
        const float e1 = fmaf(fa.y, ga.y, 1.0f);
        const float e2 = fmaf(fa.z, ga.z, 1.0f);
        const float e3 = fmaf(fa.w, ga.w, 1.0f);
        // paired reciprocals: 2 rcp for 4 evals
        const float rp01 = rcp_fast(e0 * e1);
        const float rp23 = rcp_fast(e2 * e3);
        const u32 m0 = tanh_magic_from_r(e1 * rp01);
        const u32 m1 = tanh_magic_from_r(e0 * rp01);
        const u32 m2 = tanh_magic_from_r(e3 * rp23);
        const u32 m3 = tanh_magic_from_r(e2 * rp23);
        const u32 p01 = perm_b32(m1, m0, 0x0C0C0400u);
        const u32 p23 = perm_b32(m3, m2, 0x0C0C0400u);
        wds[q] = perm_b32(p23, p01, 0x05040100u);
      }
      ((uint4*)xs)[s * 32 + row] = make_uint4(wds[0], wds[1], wds[2], wds[3]);
    }
  }
  __syncthreads();  // only block-wide barrier before epilogue

  // ---- K-loop ----
  const i32x4* xsv = (const i32x4*)xs;
  const int abase = lhi * 32 + llo;                       // + ks*64
  const uint4* w2v = (const uint4*)W2q + w * 128 + lane;  // + ks*1024, +64 for ntl=1

  i32x4 aP0 = xsv[abase];
  i32x4 aP1 = xsv[64 + abase];
  uint4 bP00 = w2v[0], bP01 = w2v[64];
  uint4 bP10 = w2v[1024], bP11 = w2v[1024 + 64];

#pragma unroll
  for (int kk = 0; kk < 8; ++kk) {
    const int ks0 = 2 * kk;
    {
      const i32x4 a = aP0;
      const i32x4 c0 = __builtin_bit_cast(i32x4, bP00);
      const i32x4 c1 = __builtin_bit_cast(i32x4, bP01);
      if (kk < 7) {
        aP0 = xsv[(ks0 + 2) * 64 + abase];
        const uint4* wp = w2v + (ks0 + 2) * 1024;
        bP00 = wp[0];
        bP01 = wp[64];
      }
      acc[0] = __builtin_amdgcn_mfma_i32_32x32x32_i8(a, c0, acc[0], 0, 0, 0);
      acc[1] = __builtin_amdgcn_mfma_i32_32x32x32_i8(a, c1, acc[1], 0, 0, 0);
    }
    {
      const i32x4 a = aP1;
      const i32x4 c0 = __builtin_bit_cast(i32x4, bP10);
      const i32x4 c1 = __builtin_bit_cast(i32x4, bP11);
      if (kk < 7) {
        aP1 = xsv[(ks0 + 3) * 64 + abase];
        const uint4* wp = w2v + (ks0 + 3) * 1024;
        bP10 = wp[0];
        bP11 = wp[64];
      }
      acc[0] = __builtin_amdgcn_mfma_i32_32x32x32_i8(a, c0, acc[0], 0, 0, 0);
      acc[1] = __builtin_amdgcn_mfma_i32_32x32x32_i8(a, c1, acc[1], 0, 0, 0);
    }
  }

  // ---- epilogue: y = acc*SCALE + b2*C2; r = 1/(exp2(y)+1) (rcp paired); partial = Σw3 - 2 Σ w3·r ----
  const float SCALE = (0.25f / (127.0f * 127.0f)) * C2;
  float b2c[2], w3v[2];
#pragma unroll
  for (int ntl = 0; ntl < 2; ++ntl) {
    const int n = w * 64 + ntl * 32 + llo;
    b2c[ntl] = b2[n] * C2;
    w3v[ntl] = W3[n];
  }
  const float w3s = half32_sum(w3v[0] + w3v[1]);  // valid in lanes 31/63

#pragma unroll
  for (int reg = 0; reg < 16; ++reg) {
    const float y0 = fmaf((float)acc[0][reg], SCALE, b2c[0]);
    const float y1 = fmaf((float)acc[1][reg], SCALE, b2c[1]);
    const float e0 = exp2_fast(y0) + 1.0f;
    const float e1 = exp2_fast(y1) + 1.0f;
    const float rp = rcp_fast(e0 * e1);  // 1 rcp for both ntl
    const float r0 = e1 * rp;
    const float r1 = e0 * rp;
    float sr = fmaf(w3v[0], r0, w3v[1] * r1);
    sr = half32_sum(sr);  // lanes 31/63 hold the 32-lane sums for lhi = 0/1
    const int row = (reg & 3) + 8 * (reg >> 2) + 4 * lhi;  // 0..31
    if (llo == 31) red[w][row] = fmaf(-2.0f, sr, w3s);
  }
  __syncthreads();
  if (t < 32) {
    float v = b3[0];
#pragma unroll
    for (int ww = 0; ww < 8; ++ww) v += red[ww][t];
    const int j = j0 + t;
    out[i * NB + j] = (j == i) ? -20.0f : v;
  }
}

extern "C" void kernel_launch(void* const* d_in, const int* in_sizes, int n_in,
                              void* d_out, int out_size, void* d_ws, size_t ws_size,
                              hipStream_t stream) {
  const float* h = (const float*)d_in[0];
  const float* W1 = (const float*)d_in[1];
  const float* b1 = (const float*)d_in[2];
  const float* W2 = (const float*)d_in[3];
  const float* b2 = (const float*)d_in[4];
  const float* W3 = (const float*)d_in[5];
  const float* b3 = (const float*)d_in[6];
  float* out = (float*)d_out;

  float* Ei = (float*)d_ws;
  float* Ej = Ei + NB * NH;
  u8* W2q = (u8*)(Ej + NB * NH);

  prep_all<<<576, 256, 0, stream>>>(h, W1, b1, W2, Ei, Ej, W2q);
  pair_main<<<8192, 512, 0, stream>>>(Ei, Ej, W2q, b2, W3, b3, out);
}